// Round 8
// baseline (191.940 us; speedup 1.0000x reference)
//
#include <hip/hip_runtime.h>
#include <hip/hip_bf16.h>

#define BS 8
#define NH 4
#define NSEQ 2048
#define FIN 64
#define FOUT 32
#define CH 32
#define BHH (BS*NH)
#define NB 256
#define LOG2E 1.44269504088896340736f

typedef float f32x4 __attribute__((ext_vector_type(4)));

// ---- small scratch in d_ws (floats) ----
#define WSS_SE    0
#define WSS_DE    (WSS_SE + BHH*NSEQ)
#define WSS_INVL  (WSS_DE + BHH*NSEQ)
#define WSS_TBLP  (WSS_INVL + BHH*NSEQ)           // [BHH][NB+1][33] suffix tables (vec+scalar)
#define WSS_TBLN  (WSS_TBLP + BHH*(NB+1)*33)      // [BHH][NB+1][33] prefix tables
#define WSS_FTOT  (WSS_TBLN + BHH*(NB+1)*33)      // ~740K floats = 3 MB

// ---- big scratch in tail of d_out's attn region (consumed before K3 writes) ----
#define BIG_HP    0                                // [BHH][NSEQ][CH]
#define BIG_GCHP  (BIG_HP + BHH*NSEQ*CH)           // [BHH][16][NB][33] per-chunk bin sums (P)
#define BIG_GCHN  (BIG_GCHP + BHH*16*NB*33)        // [BHH][16][NB][33] (N)
#define BIG_UBP   (BIG_GCHN + BHH*16*NB*33)        // [BHH][NB][33] reduced (P)
#define BIG_UBN   (BIG_UBP + BHH*NB*33)            // [BHH][NB][33] reduced (N)
#define BIG_TOTAL (BIG_UBN + BHH*NB*33)            // ~45 MB << attn (537 MB)

__device__ __forceinline__ int bin_of(float v) {
    int b = (int)((v + 8.0f) * 16.0f);
    return b < 0 ? 0 : (b > NB-1 ? NB-1 : b);
}
__device__ __forceinline__ int qbin_of(float tau) {
    int b = (int)((tau + 8.0f) * 16.0f);
    return b < 0 ? 0 : (b > NB ? NB : b);
}

// K1: h_prime = h @ w per head; s = hp.a_src, d = hp.a_dst (log2-scaled)
__global__ __launch_bounds__(256) void k1_proj(
    const float* __restrict__ h, const float* __restrict__ w,
    const float* __restrict__ asrc, const float* __restrict__ adst,
    float* __restrict__ ws, float* __restrict__ big)
{
    __shared__ float hl[64*65];
    const int b  = blockIdx.x >> 5;
    const int i0 = (blockIdx.x & 31) * 64;
    const int tid = threadIdx.x;
    const float* hsrc = h + ((size_t)b*NSEQ + i0)*FIN;
    for (int x = tid; x < 64*64; x += 256) hl[(x>>6)*65 + (x&63)] = hsrc[x];
    __syncthreads();
    const int head = __builtin_amdgcn_readfirstlane(tid >> 6);
    const int r = tid & 63;
    const int i = i0 + r;
    float acc[FOUT];
#pragma unroll
    for (int o=0;o<FOUT;o++) acc[o]=0.f;
    const float* wh = w + head*FIN*FOUT;
    for (int f=0; f<FIN; f++) {
        const float hv = hl[r*65+f];
#pragma unroll
        for (int o=0;o<FOUT;o++) acc[o] += hv * wh[f*FOUT+o];
    }
    const float* as = asrc + head*FOUT;
    const float* ad = adst + head*FOUT;
    float s=0.f, d=0.f;
#pragma unroll
    for (int o=0;o<FOUT;o++){ s += acc[o]*as[o]; d += acc[o]*ad[o]; }
    const int bh = b*NH + head;
    float* hp = big + BIG_HP + ((size_t)bh*NSEQ + i)*CH;
#pragma unroll
    for (int o=0;o<FOUT;o+=4) { f32x4 v = {acc[o],acc[o+1],acc[o+2],acc[o+3]}; *(f32x4*)(hp+o)=v; }
    ws[WSS_SE + bh*NSEQ + i] = s * LOG2E;
    ws[WSS_DE + bh*NSEQ + i] = d * LOG2E;
}

// KA: per (bh, 128-row chunk): accumulate LDS bin tables (no sort, no gather), write chunk tables.
__global__ __launch_bounds__(256) void ka_bins(
    const float* __restrict__ ws, const float* __restrict__ big_ro, float* __restrict__ big)
{
    __shared__ float bP[NB][33];
    __shared__ float bN[NB][33];
    const int bid = blockIdx.x;
    const int bh = bid >> 4, c = bid & 15;
    const int tid = threadIdx.x;
    float* fP = (float*)bP; float* fN = (float*)bN;
    for (int x = tid; x < NB*33; x += 256) { fP[x]=0.f; fN[x]=0.f; }
    __syncthreads();
    const int rr0 = tid >> 5, ch = tid & 31;
    const float* hpb = big_ro + BIG_HP + (size_t)bh*NSEQ*CH;
#pragma unroll 4
    for (int t=0; t<16; t++) {
        const int r = c*128 + t*8 + rr0;
        const float d = ws[WSS_DE + bh*NSEQ + r];
        const float wP = __builtin_amdgcn_exp2f(d);
        const float wN = __builtin_amdgcn_exp2f(0.2f*d);
        const float v  = hpb[(size_t)r*CH + ch];
        const int b = bin_of(d);
        atomicAdd(&bP[b][ch], wP*v);
        atomicAdd(&bN[b][ch], wN*v);
        if (ch == 0) { atomicAdd(&bP[b][32], wP); atomicAdd(&bN[b][32], wN); }
    }
    __syncthreads();
    const size_t baseP = BIG_GCHP + (size_t)(bh*16 + c)*NB*33;
    const size_t baseN = BIG_GCHN + (size_t)(bh*16 + c)*NB*33;
    for (int x = tid; x < NB*33; x += 256) { big[baseP+x]=fP[x]; big[baseN+x]=fN[x]; }
}

// KB1: reduce 16 chunk tables -> per-bh unscanned bin tables (256 blocks, parallel).
__global__ __launch_bounds__(256) void kb1_reduce(float* __restrict__ big)
{
    const int bid = blockIdx.x;
    const int bh = bid >> 3, g = bid & 7;           // g: 32-bin range
    const int tid = threadIdx.x;
    for (int e = tid; e < 32*33; e += 256) {
        const int bin = g*32 + e/33, ch = e - (e/33)*33;
        float sP = 0.f, sN = 0.f;
#pragma unroll
        for (int c2=0; c2<16; c2++) {
            sP += big[BIG_GCHP + ((size_t)(bh*16 + c2)*NB + bin)*33 + ch];
            sN += big[BIG_GCHN + ((size_t)(bh*16 + c2)*NB + bin)*33 + ch];
        }
        big[BIG_UBP + ((size_t)bh*NB + bin)*33 + ch] = sP;
        big[BIG_UBN + ((size_t)bh*NB + bin)*33 + ch] = sN;
    }
}

// KB2: per bh (tiny): suffix/prefix scans over 256 bins; per-row inv; write TBL tables.
__global__ __launch_bounds__(1024) void kb2_scan(
    float* __restrict__ ws, const float* __restrict__ big)
{
    __shared__ float uP[NB][33];
    __shared__ float uN[NB][33];
    __shared__ float segP[33][16], segN[33][16];
    __shared__ float totN[33];
    const int bh = blockIdx.x;
    const int tid = threadIdx.x;
    float* fP = (float*)uP; float* fN = (float*)uN;
    for (int x = tid; x < NB*33; x += 1024) {
        fP[x] = big[BIG_UBP + (size_t)bh*NB*33 + x];
        fN[x] = big[BIG_UBN + (size_t)bh*NB*33 + x];
    }
    __syncthreads();
    // pass A: segment totals (16 segments of 16 bins, 33 channels)
    if (tid < 528) {
        const int ch = tid >> 4, seg = tid & 15;
        float aP=0.f, aN=0.f;
#pragma unroll
        for (int i=0;i<16;i++){ aP += uP[seg*16+i][ch]; aN += uN[seg*16+i][ch]; }
        segP[ch][seg]=aP; segN[ch][seg]=aN;
    }
    __syncthreads();
    // pass B: scan segment totals (suffix for P, prefix for N)
    if (tid < 33) {
        float a=0.f;
        for (int s=15;s>=0;s--){ const float t=segP[tid][s]; segP[tid][s]=a; a+=t; }
        a=0.f;
        for (int s=0;s<16;s++){ const float t=segN[tid][s]; segN[tid][s]=a; a+=t; }
        totN[tid]=a;
    }
    __syncthreads();
    // pass C: in-place scans within segments (P: inclusive suffix; N: exclusive prefix)
    if (tid < 528) {
        const int ch = tid >> 4, seg = tid & 15;
        float acc = segP[ch][seg];
        for (int i=15;i>=0;i--){ acc += uP[seg*16+i][ch]; uP[seg*16+i][ch] = acc; }
        acc = segN[ch][seg];
        for (int i=0;i<16;i++){ const float t=uN[seg*16+i][ch]; uN[seg*16+i][ch]=acc; acc+=t; }
    }
    __syncthreads();
    // write TBL tables [NB+1][33]
    const size_t tb = (size_t)bh*(NB+1)*33;
    for (int x = tid; x < NB*33; x += 1024) {
        ws[WSS_TBLP + tb + x] = fP[x];
        ws[WSS_TBLN + tb + x] = fN[x];
    }
    if (tid < 33) {
        ws[WSS_TBLP + tb + NB*33 + tid] = 0.f;
        ws[WSS_TBLN + tb + NB*33 + tid] = totN[tid];
    }
    // per-row: l, inv
#pragma unroll
    for (int half=0; half<2; half++) {
        const int i = tid + half*1024;
        const float sp = ws[WSS_SE + bh*NSEQ + i];
        const int bq = qbin_of(-sp);
        const float Ss = (bq < NB) ? uP[bq][32] : 0.f;
        const float Ns = (bq < NB) ? uN[bq][32] : totN[32];
        const float e1 = __builtin_amdgcn_exp2f(sp);
        const float e2 = __builtin_amdgcn_exp2f(0.2f*sp);
        ws[WSS_INVL + bh*NSEQ + i] = 1.0f / (e1*Ss + e2*Ns);
    }
}

// K3: slim prologue (no binsearch, 17KB LDS); outp from L2-hot TBL; stream 32 attn rows.
__global__ __launch_bounds__(256) void k3_stream(
    const float* __restrict__ ws, const float* __restrict__ bvec,
    float* __restrict__ outp, float* __restrict__ attn)
{
    __shared__ float E1[NSEQ], E2[NSEQ];
    __shared__ float rA[32], rB[32], rT[32], re1[32], re2[32], rinv[32];
    __shared__ int   rBQ[32];
    const int bid = blockIdx.x;                   // 2048 = 8 XCDs x 256
    const int swz = (bid & 7) * 256 + (bid >> 3); // contiguous slab per XCD
    const int bh = swz >> 6;
    const int i0 = (swz & 63) * 32;
    const int tid = threadIdx.x;
    const int wv = tid>>6, lane = tid&63;

    for (int x = tid; x < NSEQ; x += 256) {
        const float d = ws[WSS_DE + bh*NSEQ + x];
        E1[x] = __builtin_amdgcn_exp2f(d);
        E2[x] = __builtin_amdgcn_exp2f(0.2f*d);
    }
    if (tid < 32) {
        const float sp  = ws[WSS_SE   + bh*NSEQ + i0 + tid];
        const float inv = ws[WSS_INVL + bh*NSEQ + i0 + tid];
        const float e1 = __builtin_amdgcn_exp2f(sp);
        const float e2 = __builtin_amdgcn_exp2f(0.2f*sp);
        re1[tid]=e1; re2[tid]=e2; rinv[tid]=inv;
        rA[tid]=e1*inv; rB[tid]=e2*inv;
        rT[tid]=__builtin_amdgcn_exp2f(-sp);
        rBQ[tid]=qbin_of(-sp);
    }
    __syncthreads();

    {   // outp rows: 4 waves x 8 rows, TBL lookups (L2-hot, 2.2MB)
        const int half = lane >> 5, ch = lane & 31;
        const float bval = bvec[ch];
        const size_t tb = (size_t)bh*(NB+1)*33;
        const size_t ob = (size_t)bh*NSEQ;
#pragma unroll
        for (int t=0; t<4; t++) {
            const int r = wv*8 + t*2 + half;
            const int bq = rBQ[r];
            const float S = ws[WSS_TBLP + tb + (size_t)bq*33 + ch];
            const float N = ws[WSS_TBLN + tb + (size_t)bq*33 + ch];
            outp[(ob + i0 + r)*CH + ch] = (re1[r]*S + re2[r]*N)*rinv[r] + bval;
        }
    }

    // attn stream: 32 rows x 2048, zero transcendentals, exact per-element branch
    float A[8], B[8], T[8];
#pragma unroll
    for (int k=0;k<8;k++){ A[k]=rA[wv*8+k]; B[k]=rB[wv*8+k]; T[k]=rT[wv*8+k]; }
    float* rbase = attn + ((size_t)bh*NSEQ + i0 + wv*8)*NSEQ;
#pragma unroll
    for (int blk=0; blk<8; blk++) {
        const int j0 = blk*256 + lane*4;
        const f32x4 e1 = *(const f32x4*)&E1[j0];
        const f32x4 e2 = *(const f32x4*)&E2[j0];
#pragma unroll
        for (int k=0;k<8;k++) {
            f32x4 p;
            p.x = (e1.x >= T[k]) ? A[k]*e1.x : B[k]*e2.x;
            p.y = (e1.y >= T[k]) ? A[k]*e1.y : B[k]*e2.y;
            p.z = (e1.z >= T[k]) ? A[k]*e1.z : B[k]*e2.z;
            p.w = (e1.w >= T[k]) ? A[k]*e1.w : B[k]*e2.w;
            *(f32x4*)(rbase + (size_t)k*NSEQ + j0) = p;
        }
    }
}

extern "C" void kernel_launch(void* const* d_in, const int* in_sizes, int n_in,
                              void* d_out, int out_size, void* d_ws, size_t ws_size,
                              hipStream_t stream)
{
    (void)in_sizes; (void)n_in; (void)out_size; (void)ws_size;
    const float* h    = (const float*)d_in[0];
    const float* w    = (const float*)d_in[1];
    const float* asrc = (const float*)d_in[2];
    const float* adst = (const float*)d_in[3];
    const float* bvec = (const float*)d_in[4];
    float* outp = (float*)d_out;
    float* attn = outp + (size_t)BHH*NSEQ*FOUT;
    // big scratch in the TAIL of the attn region; fully consumed before k3_stream writes
    float* big  = attn + (size_t)BHH*NSEQ*NSEQ - BIG_TOTAL;
    float* ws   = (float*)d_ws;   // needs ~3 MB

    k1_proj    <<<BS*32,   256, 0, stream>>>(h, w, asrc, adst, ws, big);
    ka_bins    <<<BHH*16,  256, 0, stream>>>(ws, big, big);
    kb1_reduce <<<BHH*8,   256, 0, stream>>>(big);
    kb2_scan   <<<BHH,    1024, 0, stream>>>(ws, big);
    k3_stream  <<<BHH*64,  256, 0, stream>>>(ws, bvec, outp, attn);
}